// Round 10
// baseline (170.698 us; speedup 1.0000x reference)
//
#include <hip/hip_runtime.h>
#include <hip/hip_fp16.h>
#include <math.h>

#define N_NODES 50000
#define E_EDGES 800000
#define IN_CH   128
#define OUT_CH  128   // HEADS*HID
#define HID     64
#define NEG_SLOPE 0.2f
#define NBLK_SCAN ((N_NODES + 255) / 256)   // 196
#define XS_STRIDE 136                       // 128 + 8 fp16 pad (272B rows)

typedef _Float16 half8 __attribute__((ext_vector_type(8)));
typedef float f32x4 __attribute__((ext_vector_type(4)));

// ============ CSR build ============

// 2 edges per thread; atomicAdd's return value IS the edge's rank within its
// dst segment -> stored for an atomic-free scatter.
__global__ void count_kernel(const int* __restrict__ ei, int* __restrict__ counts,
                             int* __restrict__ rank) {
    int t = blockIdx.x * blockDim.x + threadIdx.x;
    if (t * 2 < E_EDGES) {
        int2 d = *(const int2*)(ei + E_EDGES + t * 2);
        int2 r;
        r.x = atomicAdd(&counts[d.x], 1);
        r.y = atomicAdd(&counts[d.y], 1);
        *(int2*)(rank + t * 2) = r;
    }
}

__global__ __launch_bounds__(256) void scan1_kernel(const int* __restrict__ counts,
                                                    int* __restrict__ off,
                                                    int* __restrict__ tops) {
    __shared__ int s[256];
    int i = blockIdx.x * 256 + threadIdx.x;
    int v = (i < N_NODES) ? counts[i] : 0;
    s[threadIdx.x] = v;
    __syncthreads();
    for (int dlt = 1; dlt < 256; dlt <<= 1) {
        int t = (threadIdx.x >= dlt) ? s[threadIdx.x - dlt] : 0;
        __syncthreads();
        s[threadIdx.x] += t;
        __syncthreads();
    }
    if (i < N_NODES) off[i] = s[threadIdx.x] - v;   // exclusive within block
    if (threadIdx.x == 255) tops[blockIdx.x] = s[255];
}

__global__ __launch_bounds__(256) void scan2_kernel(int* __restrict__ tops) {
    __shared__ int s[256];
    int v = (threadIdx.x < NBLK_SCAN) ? tops[threadIdx.x] : 0;
    s[threadIdx.x] = v;
    __syncthreads();
    for (int dlt = 1; dlt < 256; dlt <<= 1) {
        int t = (threadIdx.x >= dlt) ? s[threadIdx.x - dlt] : 0;
        __syncthreads();
        s[threadIdx.x] += t;
        __syncthreads();
    }
    if (threadIdx.x < NBLK_SCAN) tops[threadIdx.x] = s[threadIdx.x] - v;  // exclusive
}

// atomic-free scatter: pos = segment start + precomputed rank
__global__ void scatter_kernel(const int* __restrict__ ei, const int* __restrict__ off,
                               const int* __restrict__ tops, const int* __restrict__ rank,
                               int* __restrict__ ssrc) {
    int t = blockIdx.x * blockDim.x + threadIdx.x;
    if (t * 2 >= E_EDGES) return;
    int2 d = *(const int2*)(ei + E_EDGES + t * 2);
    int2 s = *(const int2*)(ei + t * 2);
    int2 r = *(const int2*)(rank + t * 2);
    ssrc[tops[d.x >> 8] + off[d.x] + r.x] = s.x;
    ssrc[tops[d.y >> 8] + off[d.y] + r.y] = s.y;
}

// ============ prep: W16T[n][k] fp16 (n<128: Wl col n; else Wr col n-128), bcat ============
__global__ __launch_bounds__(256) void convW_kernel(
    const float* __restrict__ Wl, const float* __restrict__ bl,
    const float* __restrict__ Wr, const float* __restrict__ br,
    __half* __restrict__ W16T, float* __restrict__ bcat) {
    const int k = blockIdx.x;        // 0..127
    const int n = threadIdx.x;       // 0..255
    const float v = (n < 128) ? Wl[k * 128 + n] : Wr[k * 128 + (n - 128)];
    W16T[n * 128 + k] = __float2half_rn(v);
    if (k == 0) bcat[n] = (n < 128) ? bl[n] : br[n - 128];
}

// ============ dense via MFMA: [xl16|xr] = x @ [Wl|Wr] + [bl|br] ============
// 256 threads = 4 waves; 64 nodes/block (wave wv owns nodes wv*16..+15).
// A-frag: lane l holds xs[m = l&15][k = s*32 + (l>>4)*8 + j] (8 fp16, ds_read_b128).
// B-frag: lane l holds W16T[n = t*16 + (l&15)][same k] (8 fp16, global 16B).
// C/D: col = lane&15 (n), row = (lane>>4)*4 + reg (m)  [HW-verified mapping].
__global__ __launch_bounds__(256) void linear_mfma_kernel(
    const float* __restrict__ x, const __half* __restrict__ W16T,
    const float* __restrict__ bcat,
    __half* __restrict__ xl16, float* __restrict__ xr) {
    __shared__ __align__(16) __half xs[64 * XS_STRIDE];
    const int tid  = threadIdx.x;
    const int lane = tid & 63;
    const int wv   = tid >> 6;
    const int nodeBase = blockIdx.x * 64;

    // stage x tile fp32 -> fp16 LDS (padded rows)
    {
        const float4* __restrict__ x4 = (const float4*)(x + (size_t)nodeBase * IN_CH);
        #pragma unroll
        for (int i = 0; i < 8; ++i) {
            const int idx = tid + i * 256;      // float4 index in [0,2048)
            const int row = idx >> 5;           // node within tile
            const int c   = (idx & 31) * 4;     // starting col
            float4 v = {0.0f, 0.0f, 0.0f, 0.0f};
            if (nodeBase + row < N_NODES) v = x4[idx];
            __half2 h01 = __floats2half2_rn(v.x, v.y);
            __half2 h23 = __floats2half2_rn(v.z, v.w);
            uint2 pk;
            pk.x = *(unsigned int*)&h01;
            pk.y = *(unsigned int*)&h23;
            *(uint2*)&xs[row * XS_STRIDE + c] = pk;   // 272B rows: 8B-aligned
        }
    }
    __syncthreads();

    const half8* __restrict__ wt = (const half8*)W16T;
    const int q16 = lane & 15;    // m for A, n-offset for B, col for C
    const int kg  = lane >> 4;    // k-group 0..3

    f32x4 acc[16];
    #pragma unroll
    for (int t = 0; t < 16; ++t) acc[t] = (f32x4){0.0f, 0.0f, 0.0f, 0.0f};

    #pragma unroll
    for (int s = 0; s < 4; ++s) {
        const half8 a = *(const half8*)&xs[(wv * 16 + q16) * XS_STRIDE + s * 32 + kg * 8];
        #pragma unroll
        for (int t = 0; t < 16; ++t) {
            const half8 b = wt[(t * 16 + q16) * 16 + s * 4 + kg];
            acc[t] = __builtin_amdgcn_mfma_f32_16x16x32_f16(a, b, acc[t], 0, 0, 0);
        }
    }

    // epilogue: bias + split stores (cols <128 -> xl16 fp16, >=128 -> xr fp32)
    const int nodeRow0 = nodeBase + wv * 16 + kg * 4;
    #pragma unroll
    for (int t = 0; t < 16; ++t) {
        const int col = t * 16 + q16;
        const float bv = bcat[col];
        #pragma unroll
        for (int r = 0; r < 4; ++r) {
            const int node = nodeRow0 + r;
            if (node < N_NODES) {
                const float v = acc[t][r] + bv;
                if (col < 128) xl16[(size_t)node * 128 + col] = __float2half_rn(v);
                else           xr[(size_t)node * 128 + (col - 128)] = v;
            }
        }
    }
}

// ============ fused per-node softmax aggregation (unchanged) ============
__global__ __launch_bounds__(256) void node_agg_kernel(
    const __half* __restrict__ xl16, const float* __restrict__ xr,
    const float* __restrict__ att,
    const int* __restrict__ off, const int* __restrict__ counts,
    const int* __restrict__ tops, const int* __restrict__ ssrc,
    const float* __restrict__ bias, float* __restrict__ out) {
    const int node = (blockIdx.x * blockDim.x + threadIdx.x) >> 6;
    const int lane = threadIdx.x & 63;
    if (node >= N_NODES) return;
    const int half = lane >> 5;
    const int cl   = lane & 31;

    const uint2* __restrict__ xlh = (const uint2*)xl16;
    const float4 xrv  = ((const float4*)xr)[node * 32 + cl];
    const float4 attv = ((const float4*)att)[cl];

    const int cnt = counts[node];
    const int o   = tops[node >> 8] + off[node];

    float d = 0.0f;
    float4 acc = {0.0f, 0.0f, 0.0f, 0.0f};

#define LOADV(raw, v)                                                        \
    {                                                                        \
        __half2 h01 = *(__half2*)&raw.x;                                     \
        __half2 h23 = *(__half2*)&raw.y;                                     \
        float2 f01 = __half22float2(h01);                                    \
        float2 f23 = __half22float2(h23);                                    \
        v.x = f01.x; v.y = f01.y; v.z = f23.x; v.w = f23.y;                  \
    }
#define SCORE(v, a)                                                          \
    {                                                                        \
        float s0 = v.x + xrv.x; s0 = fmaxf(s0, NEG_SLOPE * s0);              \
        float s1 = v.y + xrv.y; s1 = fmaxf(s1, NEG_SLOPE * s1);              \
        float s2 = v.z + xrv.z; s2 = fmaxf(s2, NEG_SLOPE * s2);              \
        float s3 = v.w + xrv.w; s3 = fmaxf(s3, NEG_SLOPE * s3);              \
        a = fmaf(s0, attv.x, fmaf(s1, attv.y, fmaf(s2, attv.z, s3 * attv.w))); \
    }

    int k = 0;
    for (; k + 4 <= cnt; k += 4) {
        const int sA = ssrc[o + k + half];
        const int sB = ssrc[o + k + 2 + half];
        const uint2 rA = xlh[sA * 32 + cl];
        const uint2 rB = xlh[sB * 32 + cl];
        float4 vA, vB;
        LOADV(rA, vA);
        LOADV(rB, vB);

        float a0, a1;
        SCORE(vA, a0);
        SCORE(vB, a1);
        a0 += __shfl_xor(a0, 8); a1 += __shfl_xor(a1, 8);
        a0 += __shfl_xor(a0, 4); a1 += __shfl_xor(a1, 4);
        a0 += __shfl_xor(a0, 2); a1 += __shfl_xor(a1, 2);
        a0 += __shfl_xor(a0, 1); a1 += __shfl_xor(a1, 1);
        const float wA = __expf(a0);
        const float wB = __expf(a1);
        d += wA + wB;
        acc.x = fmaf(wA, vA.x, fmaf(wB, vB.x, acc.x));
        acc.y = fmaf(wA, vA.y, fmaf(wB, vB.y, acc.y));
        acc.z = fmaf(wA, vA.z, fmaf(wB, vB.z, acc.z));
        acc.w = fmaf(wA, vA.w, fmaf(wB, vB.w, acc.w));
    }
    for (; k < cnt; k += 2) {
        const int eidx = k + half;
        const bool valid = (eidx < cnt);
        const int src = ssrc[o + (valid ? eidx : 0)];
        const uint2 raw = xlh[src * 32 + cl];
        float4 v;
        LOADV(raw, v);
        float a;
        SCORE(v, a);
        a += __shfl_xor(a, 8);
        a += __shfl_xor(a, 4);
        a += __shfl_xor(a, 2);
        a += __shfl_xor(a, 1);
        const float w = valid ? __expf(a) : 0.0f;
        d += w;
        acc.x = fmaf(w, v.x, acc.x);
        acc.y = fmaf(w, v.y, acc.y);
        acc.z = fmaf(w, v.z, acc.z);
        acc.w = fmaf(w, v.w, acc.w);
    }
#undef SCORE
#undef LOADV
    acc.x += __shfl_xor(acc.x, 32);
    acc.y += __shfl_xor(acc.y, 32);
    acc.z += __shfl_xor(acc.z, 32);
    acc.w += __shfl_xor(acc.w, 32);
    d     += __shfl_xor(d, 32);

    if (lane < 32) {
        const float4 bv = ((const float4*)bias)[cl];
        const float inv = 1.0f / (d + 1e-16f);
        float4 r;
        float t;
        t = __expf(2.0f * fmaf(acc.x, inv, bv.x)); r.x = (t - 1.0f) / (t + 1.0f);
        t = __expf(2.0f * fmaf(acc.y, inv, bv.y)); r.y = (t - 1.0f) / (t + 1.0f);
        t = __expf(2.0f * fmaf(acc.z, inv, bv.z)); r.z = (t - 1.0f) / (t + 1.0f);
        t = __expf(2.0f * fmaf(acc.w, inv, bv.w)); r.w = (t - 1.0f) / (t + 1.0f);
        ((float4*)out)[node * 32 + cl] = r;
    }
}

extern "C" void kernel_launch(void* const* d_in, const int* in_sizes, int n_in,
                              void* d_out, int out_size, void* d_ws, size_t ws_size,
                              hipStream_t stream) {
    const float* x    = (const float*)d_in[0];
    const int*   ei   = (const int*)d_in[1];
    // d_in[2] = edge_weight — unused by the reference
    const float* Wl   = (const float*)d_in[3];
    const float* bl   = (const float*)d_in[4];
    const float* Wr   = (const float*)d_in[5];
    const float* br   = (const float*)d_in[6];
    const float* att  = (const float*)d_in[7];
    const float* bias = (const float*)d_in[8];
    float* out = (float*)d_out;

    // workspace layout
    char* ws = (char*)d_ws;
    __half* xl16  = (__half*)ws;  ws += (size_t)N_NODES * OUT_CH * 2;
    float*  xr    = (float*)ws;   ws += (size_t)N_NODES * OUT_CH * 4;
    __half* W16T  = (__half*)ws;  ws += (size_t)256 * 128 * 2;
    float*  bcat  = (float*)ws;   ws += 256 * 4;
    int*   counts = (int*)ws;     ws += (size_t)N_NODES * 4;
    int*   off    = (int*)ws;     ws += (size_t)N_NODES * 4;
    int*   tops   = (int*)ws;     ws += 256 * 4;
    int*   rank   = (int*)ws;     ws += (size_t)E_EDGES * 4;
    int*   ssrc   = (int*)ws;     ws += (size_t)E_EDGES * 4;

    const int pairBlocks = (E_EDGES / 2 + 255) / 256;     // 1563

    hipMemsetAsync(counts, 0, (size_t)N_NODES * 4, stream);
    convW_kernel<<<128, 256, 0, stream>>>(Wl, bl, Wr, br, W16T, bcat);
    linear_mfma_kernel<<<(N_NODES + 63) / 64, 256, 0, stream>>>(x, W16T, bcat, xl16, xr);
    count_kernel<<<pairBlocks, 256, 0, stream>>>(ei, counts, rank);
    scan1_kernel<<<NBLK_SCAN, 256, 0, stream>>>(counts, off, tops);
    scan2_kernel<<<1, 256, 0, stream>>>(tops);
    scatter_kernel<<<pairBlocks, 256, 0, stream>>>(ei, off, tops, rank, ssrc);
    node_agg_kernel<<<(N_NODES + 3) / 4, 256, 0, stream>>>(
        xl16, xr, att, off, counts, tops, ssrc, bias, out);
}

// Round 11
// 130.748 us; speedup vs baseline: 1.3055x; 1.3055x over previous
//
#include <hip/hip_runtime.h>
#include <hip/hip_fp16.h>
#include <math.h>

#define N_NODES 50000
#define E_EDGES 800000
#define IN_CH   128
#define OUT_CH  128   // HEADS*HID
#define HID     64
#define NEG_SLOPE 0.2f
#define NBLK_SCAN ((N_NODES + 255) / 256)   // 196
#define XS_STRIDE 136                       // 128 + 8 fp16 pad (272B rows)

typedef _Float16 half8 __attribute__((ext_vector_type(8)));
typedef float f32x4 __attribute__((ext_vector_type(4)));

// ============ CSR build ============

// 2 edges per thread; atomicAdd's return value IS the edge's rank within its
// dst segment -> stored for an atomic-free scatter.
__global__ void count_kernel(const int* __restrict__ ei, int* __restrict__ counts,
                             int* __restrict__ rank) {
    int t = blockIdx.x * blockDim.x + threadIdx.x;
    if (t * 2 < E_EDGES) {
        int2 d = *(const int2*)(ei + E_EDGES + t * 2);
        int2 r;
        r.x = atomicAdd(&counts[d.x], 1);
        r.y = atomicAdd(&counts[d.y], 1);
        *(int2*)(rank + t * 2) = r;
    }
}

__global__ __launch_bounds__(256) void scan1_kernel(const int* __restrict__ counts,
                                                    int* __restrict__ off,
                                                    int* __restrict__ tops) {
    __shared__ int s[256];
    int i = blockIdx.x * 256 + threadIdx.x;
    int v = (i < N_NODES) ? counts[i] : 0;
    s[threadIdx.x] = v;
    __syncthreads();
    for (int dlt = 1; dlt < 256; dlt <<= 1) {
        int t = (threadIdx.x >= dlt) ? s[threadIdx.x - dlt] : 0;
        __syncthreads();
        s[threadIdx.x] += t;
        __syncthreads();
    }
    if (i < N_NODES) off[i] = s[threadIdx.x] - v;   // exclusive within block
    if (threadIdx.x == 255) tops[blockIdx.x] = s[255];
}

__global__ __launch_bounds__(256) void scan2_kernel(int* __restrict__ tops) {
    __shared__ int s[256];
    int v = (threadIdx.x < NBLK_SCAN) ? tops[threadIdx.x] : 0;
    s[threadIdx.x] = v;
    __syncthreads();
    for (int dlt = 1; dlt < 256; dlt <<= 1) {
        int t = (threadIdx.x >= dlt) ? s[threadIdx.x - dlt] : 0;
        __syncthreads();
        s[threadIdx.x] += t;
        __syncthreads();
    }
    if (threadIdx.x < NBLK_SCAN) tops[threadIdx.x] = s[threadIdx.x] - v;  // exclusive
}

// atomic-free scatter: pos = segment start + precomputed rank
__global__ void scatter_kernel(const int* __restrict__ ei, const int* __restrict__ off,
                               const int* __restrict__ tops, const int* __restrict__ rank,
                               int* __restrict__ ssrc) {
    int t = blockIdx.x * blockDim.x + threadIdx.x;
    if (t * 2 >= E_EDGES) return;
    int2 d = *(const int2*)(ei + E_EDGES + t * 2);
    int2 s = *(const int2*)(ei + t * 2);
    int2 r = *(const int2*)(rank + t * 2);
    ssrc[tops[d.x >> 8] + off[d.x] + r.x] = s.x;
    ssrc[tops[d.y >> 8] + off[d.y] + r.y] = s.y;
}

// ============ prep: W in MFMA-fragment order + bcat ============
// wfrag half8[p], p = ((t*4+s)*4+kg)*16 + q16 holds W^T[n=t*16+q16][k0..k0+8),
// k0 = s*32 + kg*8. A wave's B-frag load for (t,s) is then 64 CONSECUTIVE
// half8s (lane l -> p_base + l): one coalesced 1KB transaction.
__global__ __launch_bounds__(256) void convW_kernel(
    const float* __restrict__ Wl, const float* __restrict__ bl,
    const float* __restrict__ Wr, const float* __restrict__ br,
    __half* __restrict__ wfrag, float* __restrict__ bcat) {
    const int gid = blockIdx.x * 256 + threadIdx.x;   // [0, 4096)
    const int n = gid & 255;          // output col in [0,256)
    const int c = gid >> 8;           // k-chunk in [0,16)
    const int t = n >> 4, q16 = n & 15, s = c >> 2, kg = c & 3;
    const int k0 = c * 8;
    const float* __restrict__ Wsrc = (n < 128) ? Wl : Wr;
    const int col = n & 127;
    half8 h;
    #pragma unroll
    for (int j = 0; j < 8; ++j) h[j] = (_Float16)Wsrc[(k0 + j) * 128 + col];
    ((half8*)wfrag)[((t * 4 + s) * 4 + kg) * 16 + q16] = h;
    if (c == 0) bcat[n] = (n < 128) ? bl[col] : br[col];
}

// ============ dense via MFMA: [xl16|xr] = x @ [Wl|Wr] + [bl|br] ============
// 256 threads = 4 waves; 64 nodes/block. Wave wv owns OUTPUT COLS [wv*64,+64)
// for ALL 64 nodes: its 16 B-frags (64 VGPR) are hoisted ONCE, then the m-loop
// runs purely from LDS A-frags + register B-frags (no global loads in hot path).
// A-frag: lane l holds xs[m*16 + (l&15)][s*32 + (l>>4)*8 + j].
// C/D: col = lane&15, row = (lane>>4)*4 + reg  [HW-verified mapping].
__global__ __launch_bounds__(256) void linear_mfma_kernel(
    const float* __restrict__ x, const __half* __restrict__ wfrag,
    const float* __restrict__ bcat,
    __half* __restrict__ xl16, float* __restrict__ xr) {
    __shared__ __align__(16) __half xs[64 * XS_STRIDE];
    const int tid  = threadIdx.x;
    const int lane = tid & 63;
    const int wv   = tid >> 6;
    const int nodeBase = blockIdx.x * 64;

    // stage x tile fp32 -> fp16 LDS (padded rows)
    {
        const float4* __restrict__ x4 = (const float4*)(x + (size_t)nodeBase * IN_CH);
        #pragma unroll
        for (int i = 0; i < 8; ++i) {
            const int idx = tid + i * 256;      // float4 index in [0,2048)
            const int row = idx >> 5;           // node within tile
            const int c   = (idx & 31) * 4;     // starting col
            float4 v = {0.0f, 0.0f, 0.0f, 0.0f};
            if (nodeBase + row < N_NODES) v = x4[idx];
            __half2 h01 = __floats2half2_rn(v.x, v.y);
            __half2 h23 = __floats2half2_rn(v.z, v.w);
            uint2 pk;
            pk.x = *(unsigned int*)&h01;
            pk.y = *(unsigned int*)&h23;
            *(uint2*)&xs[row * XS_STRIDE + c] = pk;
        }
    }
    __syncthreads();

    const int q16 = lane & 15;
    const int kg  = lane >> 4;

    // hoist this wave's 16 B-frags (col tile wv*64, all 128 k)
    const half8* __restrict__ wf8 = (const half8*)wfrag;
    half8 b[4][4];
    #pragma unroll
    for (int t = 0; t < 4; ++t)
        #pragma unroll
        for (int s = 0; s < 4; ++s)
            b[t][s] = wf8[(((wv * 4 + t) * 4 + s) * 4 + kg) * 16 + q16];

    #pragma unroll
    for (int m = 0; m < 4; ++m) {
        f32x4 acc[4];
        #pragma unroll
        for (int t = 0; t < 4; ++t) acc[t] = (f32x4){0.0f, 0.0f, 0.0f, 0.0f};
        #pragma unroll
        for (int s = 0; s < 4; ++s) {
            const half8 a = *(const half8*)&xs[(m * 16 + q16) * XS_STRIDE + s * 32 + kg * 8];
            #pragma unroll
            for (int t = 0; t < 4; ++t)
                acc[t] = __builtin_amdgcn_mfma_f32_16x16x32_f16(a, b[t][s], acc[t], 0, 0, 0);
        }
        // epilogue for this 16-node sub-tile
        const int nodeRow0 = nodeBase + m * 16 + kg * 4;
        #pragma unroll
        for (int t = 0; t < 4; ++t) {
            const int col = wv * 64 + t * 16 + q16;
            const float bv = bcat[col];
            #pragma unroll
            for (int r = 0; r < 4; ++r) {
                const int node = nodeRow0 + r;
                if (node < N_NODES) {
                    const float v = acc[t][r] + bv;
                    if (col < 128) xl16[(size_t)node * 128 + col] = __float2half_rn(v);
                    else           xr[(size_t)node * 128 + (col - 128)] = v;
                }
            }
        }
    }
}

// ============ fused per-node softmax aggregation (unchanged) ============
__global__ __launch_bounds__(256) void node_agg_kernel(
    const __half* __restrict__ xl16, const float* __restrict__ xr,
    const float* __restrict__ att,
    const int* __restrict__ off, const int* __restrict__ counts,
    const int* __restrict__ tops, const int* __restrict__ ssrc,
    const float* __restrict__ bias, float* __restrict__ out) {
    const int node = (blockIdx.x * blockDim.x + threadIdx.x) >> 6;
    const int lane = threadIdx.x & 63;
    if (node >= N_NODES) return;
    const int half = lane >> 5;
    const int cl   = lane & 31;

    const uint2* __restrict__ xlh = (const uint2*)xl16;
    const float4 xrv  = ((const float4*)xr)[node * 32 + cl];
    const float4 attv = ((const float4*)att)[cl];

    const int cnt = counts[node];
    const int o   = tops[node >> 8] + off[node];

    float d = 0.0f;
    float4 acc = {0.0f, 0.0f, 0.0f, 0.0f};

#define LOADV(raw, v)                                                        \
    {                                                                        \
        __half2 h01 = *(__half2*)&raw.x;                                     \
        __half2 h23 = *(__half2*)&raw.y;                                     \
        float2 f01 = __half22float2(h01);                                    \
        float2 f23 = __half22float2(h23);                                    \
        v.x = f01.x; v.y = f01.y; v.z = f23.x; v.w = f23.y;                  \
    }
#define SCORE(v, a)                                                          \
    {                                                                        \
        float s0 = v.x + xrv.x; s0 = fmaxf(s0, NEG_SLOPE * s0);              \
        float s1 = v.y + xrv.y; s1 = fmaxf(s1, NEG_SLOPE * s1);              \
        float s2 = v.z + xrv.z; s2 = fmaxf(s2, NEG_SLOPE * s2);              \
        float s3 = v.w + xrv.w; s3 = fmaxf(s3, NEG_SLOPE * s3);              \
        a = fmaf(s0, attv.x, fmaf(s1, attv.y, fmaf(s2, attv.z, s3 * attv.w))); \
    }

    int k = 0;
    for (; k + 4 <= cnt; k += 4) {
        const int sA = ssrc[o + k + half];
        const int sB = ssrc[o + k + 2 + half];
        const uint2 rA = xlh[sA * 32 + cl];
        const uint2 rB = xlh[sB * 32 + cl];
        float4 vA, vB;
        LOADV(rA, vA);
        LOADV(rB, vB);

        float a0, a1;
        SCORE(vA, a0);
        SCORE(vB, a1);
        a0 += __shfl_xor(a0, 8); a1 += __shfl_xor(a1, 8);
        a0 += __shfl_xor(a0, 4); a1 += __shfl_xor(a1, 4);
        a0 += __shfl_xor(a0, 2); a1 += __shfl_xor(a1, 2);
        a0 += __shfl_xor(a0, 1); a1 += __shfl_xor(a1, 1);
        const float wA = __expf(a0);
        const float wB = __expf(a1);
        d += wA + wB;
        acc.x = fmaf(wA, vA.x, fmaf(wB, vB.x, acc.x));
        acc.y = fmaf(wA, vA.y, fmaf(wB, vB.y, acc.y));
        acc.z = fmaf(wA, vA.z, fmaf(wB, vB.z, acc.z));
        acc.w = fmaf(wA, vA.w, fmaf(wB, vB.w, acc.w));
    }
    for (; k < cnt; k += 2) {
        const int eidx = k + half;
        const bool valid = (eidx < cnt);
        const int src = ssrc[o + (valid ? eidx : 0)];
        const uint2 raw = xlh[src * 32 + cl];
        float4 v;
        LOADV(raw, v);
        float a;
        SCORE(v, a);
        a += __shfl_xor(a, 8);
        a += __shfl_xor(a, 4);
        a += __shfl_xor(a, 2);
        a += __shfl_xor(a, 1);
        const float w = valid ? __expf(a) : 0.0f;
        d += w;
        acc.x = fmaf(w, v.x, acc.x);
        acc.y = fmaf(w, v.y, acc.y);
        acc.z = fmaf(w, v.z, acc.z);
        acc.w = fmaf(w, v.w, acc.w);
    }
#undef SCORE
#undef LOADV
    acc.x += __shfl_xor(acc.x, 32);
    acc.y += __shfl_xor(acc.y, 32);
    acc.z += __shfl_xor(acc.z, 32);
    acc.w += __shfl_xor(acc.w, 32);
    d     += __shfl_xor(d, 32);

    if (lane < 32) {
        const float4 bv = ((const float4*)bias)[cl];
        const float inv = 1.0f / (d + 1e-16f);
        float4 r;
        float t;
        t = __expf(2.0f * fmaf(acc.x, inv, bv.x)); r.x = (t - 1.0f) / (t + 1.0f);
        t = __expf(2.0f * fmaf(acc.y, inv, bv.y)); r.y = (t - 1.0f) / (t + 1.0f);
        t = __expf(2.0f * fmaf(acc.z, inv, bv.z)); r.z = (t - 1.0f) / (t + 1.0f);
        t = __expf(2.0f * fmaf(acc.w, inv, bv.w)); r.w = (t - 1.0f) / (t + 1.0f);
        ((float4*)out)[node * 32 + cl] = r;
    }
}

extern "C" void kernel_launch(void* const* d_in, const int* in_sizes, int n_in,
                              void* d_out, int out_size, void* d_ws, size_t ws_size,
                              hipStream_t stream) {
    const float* x    = (const float*)d_in[0];
    const int*   ei   = (const int*)d_in[1];
    // d_in[2] = edge_weight — unused by the reference
    const float* Wl   = (const float*)d_in[3];
    const float* bl   = (const float*)d_in[4];
    const float* Wr   = (const float*)d_in[5];
    const float* br   = (const float*)d_in[6];
    const float* att  = (const float*)d_in[7];
    const float* bias = (const float*)d_in[8];
    float* out = (float*)d_out;

    // workspace layout
    char* ws = (char*)d_ws;
    __half* xl16  = (__half*)ws;  ws += (size_t)N_NODES * OUT_CH * 2;
    float*  xr    = (float*)ws;   ws += (size_t)N_NODES * OUT_CH * 4;
    __half* wfrag = (__half*)ws;  ws += (size_t)256 * 128 * 2;
    float*  bcat  = (float*)ws;   ws += 256 * 4;
    int*   counts = (int*)ws;     ws += (size_t)N_NODES * 4;
    int*   off    = (int*)ws;     ws += (size_t)N_NODES * 4;
    int*   tops   = (int*)ws;     ws += 256 * 4;
    int*   rank   = (int*)ws;     ws += (size_t)E_EDGES * 4;
    int*   ssrc   = (int*)ws;     ws += (size_t)E_EDGES * 4;

    const int pairBlocks = (E_EDGES / 2 + 255) / 256;     // 1563

    hipMemsetAsync(counts, 0, (size_t)N_NODES * 4, stream);
    convW_kernel<<<16, 256, 0, stream>>>(Wl, bl, Wr, br, wfrag, bcat);
    linear_mfma_kernel<<<(N_NODES + 63) / 64, 256, 0, stream>>>(x, wfrag, bcat, xl16, xr);
    count_kernel<<<pairBlocks, 256, 0, stream>>>(ei, counts, rank);
    scan1_kernel<<<NBLK_SCAN, 256, 0, stream>>>(counts, off, tops);
    scan2_kernel<<<1, 256, 0, stream>>>(tops);
    scatter_kernel<<<pairBlocks, 256, 0, stream>>>(ei, off, tops, rank, ssrc);
    node_agg_kernel<<<(N_NODES + 3) / 4, 256, 0, stream>>>(
        xl16, xr, att, off, counts, tops, ssrc, bias, out);
}

// Round 12
// 124.567 us; speedup vs baseline: 1.3703x; 1.0496x over previous
//
#include <hip/hip_runtime.h>
#include <hip/hip_fp16.h>
#include <math.h>

#define N_NODES 50000
#define E_EDGES 800000
#define IN_CH   128
#define OUT_CH  128   // HEADS*HID
#define HID     64
#define NEG_SLOPE 0.2f
#define NBLK_SCAN ((N_NODES + 255) / 256)   // 196
#define XS_STRIDE 136                       // 128 + 8 fp16 pad (272B rows)

typedef _Float16 half8 __attribute__((ext_vector_type(8)));
typedef float f32x4 __attribute__((ext_vector_type(4)));

// DPP rotation-reduce step within each 16-lane row: a += row_ror<N>(a).
// Pure VALU (no ds_swizzle / lgkmcnt) — replaces __shfl_xor for sum-reductions.
template<int CTRL>
__device__ __forceinline__ float dpp_add(float a) {
    int t = __builtin_amdgcn_update_dpp(0, __float_as_int(a), CTRL, 0xF, 0xF, true);
    return a + __int_as_float(t);
}
// row_ror:N ctrl encoding = 0x120 | N
#define REDUCE16(a)                                                          \
    a = dpp_add<0x128>(a); a = dpp_add<0x124>(a);                            \
    a = dpp_add<0x122>(a); a = dpp_add<0x121>(a);

// ============ CSR build ============

// 2 edges per thread; atomicAdd's return value IS the edge's rank within its
// dst segment -> stored for an atomic-free scatter.
__global__ void count_kernel(const int* __restrict__ ei, int* __restrict__ counts,
                             int* __restrict__ rank) {
    int t = blockIdx.x * blockDim.x + threadIdx.x;
    if (t * 2 < E_EDGES) {
        int2 d = *(const int2*)(ei + E_EDGES + t * 2);
        int2 r;
        r.x = atomicAdd(&counts[d.x], 1);
        r.y = atomicAdd(&counts[d.y], 1);
        *(int2*)(rank + t * 2) = r;
    }
}

__global__ __launch_bounds__(256) void scan1_kernel(const int* __restrict__ counts,
                                                    int* __restrict__ off,
                                                    int* __restrict__ tops) {
    __shared__ int s[256];
    int i = blockIdx.x * 256 + threadIdx.x;
    int v = (i < N_NODES) ? counts[i] : 0;
    s[threadIdx.x] = v;
    __syncthreads();
    for (int dlt = 1; dlt < 256; dlt <<= 1) {
        int t = (threadIdx.x >= dlt) ? s[threadIdx.x - dlt] : 0;
        __syncthreads();
        s[threadIdx.x] += t;
        __syncthreads();
    }
    if (i < N_NODES) off[i] = s[threadIdx.x] - v;   // exclusive within block
    if (threadIdx.x == 255) tops[blockIdx.x] = s[255];
}

__global__ __launch_bounds__(256) void scan2_kernel(int* __restrict__ tops) {
    __shared__ int s[256];
    int v = (threadIdx.x < NBLK_SCAN) ? tops[threadIdx.x] : 0;
    s[threadIdx.x] = v;
    __syncthreads();
    for (int dlt = 1; dlt < 256; dlt <<= 1) {
        int t = (threadIdx.x >= dlt) ? s[threadIdx.x - dlt] : 0;
        __syncthreads();
        s[threadIdx.x] += t;
        __syncthreads();
    }
    if (threadIdx.x < NBLK_SCAN) tops[threadIdx.x] = s[threadIdx.x] - v;  // exclusive
}

// atomic-free scatter: pos = segment start + precomputed rank
__global__ void scatter_kernel(const int* __restrict__ ei, const int* __restrict__ off,
                               const int* __restrict__ tops, const int* __restrict__ rank,
                               int* __restrict__ ssrc) {
    int t = blockIdx.x * blockDim.x + threadIdx.x;
    if (t * 2 >= E_EDGES) return;
    int2 d = *(const int2*)(ei + E_EDGES + t * 2);
    int2 s = *(const int2*)(ei + t * 2);
    int2 r = *(const int2*)(rank + t * 2);
    ssrc[tops[d.x >> 8] + off[d.x] + r.x] = s.x;
    ssrc[tops[d.y >> 8] + off[d.y] + r.y] = s.y;
}

// ============ prep: W in MFMA-fragment order + bcat + zero counts ============
// Grid 196 blocks: first 16 blocks (4096 threads) convert W; ALL blocks zero a
// slice of counts[] (replaces the hipMemsetAsync dispatch).
__global__ __launch_bounds__(256) void convW_kernel(
    const float* __restrict__ Wl, const float* __restrict__ bl,
    const float* __restrict__ Wr, const float* __restrict__ br,
    __half* __restrict__ wfrag, float* __restrict__ bcat,
    int* __restrict__ counts) {
    const int gid = blockIdx.x * 256 + threadIdx.x;
    if (gid < N_NODES) counts[gid] = 0;
    if (gid >= 4096) return;
    const int n = gid & 255;          // output col in [0,256)
    const int c = gid >> 8;           // k-chunk in [0,16)
    const int t = n >> 4, q16 = n & 15, s = c >> 2, kg = c & 3;
    const int k0 = c * 8;
    const float* __restrict__ Wsrc = (n < 128) ? Wl : Wr;
    const int col = n & 127;
    half8 h;
    #pragma unroll
    for (int j = 0; j < 8; ++j) h[j] = (_Float16)Wsrc[(k0 + j) * 128 + col];
    ((half8*)wfrag)[((t * 4 + s) * 4 + kg) * 16 + q16] = h;
    if (c == 0) bcat[n] = (n < 128) ? bl[col] : br[col];
}

// ============ dense via MFMA: [xl16|xr] = x @ [Wl|Wr] + [bl|br] ============
// 256 threads = 4 waves; 64 nodes/block. Wave wv owns OUTPUT COLS [wv*64,+64)
// for ALL 64 nodes: its 16 B-frags (64 VGPR) hoisted once; hot loop runs from
// LDS A-frags + register B-frags. C/D: col=lane&15, row=(lane>>4)*4+reg.
__global__ __launch_bounds__(256) void linear_mfma_kernel(
    const float* __restrict__ x, const __half* __restrict__ wfrag,
    const float* __restrict__ bcat,
    __half* __restrict__ xl16, float* __restrict__ xr) {
    __shared__ __align__(16) __half xs[64 * XS_STRIDE];
    const int tid  = threadIdx.x;
    const int lane = tid & 63;
    const int wv   = tid >> 6;
    const int nodeBase = blockIdx.x * 64;

    {
        const float4* __restrict__ x4 = (const float4*)(x + (size_t)nodeBase * IN_CH);
        #pragma unroll
        for (int i = 0; i < 8; ++i) {
            const int idx = tid + i * 256;      // float4 index in [0,2048)
            const int row = idx >> 5;
            const int c   = (idx & 31) * 4;
            float4 v = {0.0f, 0.0f, 0.0f, 0.0f};
            if (nodeBase + row < N_NODES) v = x4[idx];
            __half2 h01 = __floats2half2_rn(v.x, v.y);
            __half2 h23 = __floats2half2_rn(v.z, v.w);
            uint2 pk;
            pk.x = *(unsigned int*)&h01;
            pk.y = *(unsigned int*)&h23;
            *(uint2*)&xs[row * XS_STRIDE + c] = pk;
        }
    }
    __syncthreads();

    const int q16 = lane & 15;
    const int kg  = lane >> 4;

    const half8* __restrict__ wf8 = (const half8*)wfrag;
    half8 b[4][4];
    #pragma unroll
    for (int t = 0; t < 4; ++t)
        #pragma unroll
        for (int s = 0; s < 4; ++s)
            b[t][s] = wf8[(((wv * 4 + t) * 4 + s) * 4 + kg) * 16 + q16];

    #pragma unroll
    for (int m = 0; m < 4; ++m) {
        f32x4 acc[4];
        #pragma unroll
        for (int t = 0; t < 4; ++t) acc[t] = (f32x4){0.0f, 0.0f, 0.0f, 0.0f};
        #pragma unroll
        for (int s = 0; s < 4; ++s) {
            const half8 a = *(const half8*)&xs[(m * 16 + q16) * XS_STRIDE + s * 32 + kg * 8];
            #pragma unroll
            for (int t = 0; t < 4; ++t)
                acc[t] = __builtin_amdgcn_mfma_f32_16x16x32_f16(a, b[t][s], acc[t], 0, 0, 0);
        }
        const int nodeRow0 = nodeBase + m * 16 + kg * 4;
        #pragma unroll
        for (int t = 0; t < 4; ++t) {
            const int col = wv * 64 + t * 16 + q16;
            const float bv = bcat[col];
            #pragma unroll
            for (int r = 0; r < 4; ++r) {
                const int node = nodeRow0 + r;
                if (node < N_NODES) {
                    const float v = acc[t][r] + bv;
                    if (col < 128) xl16[(size_t)node * 128 + col] = __float2half_rn(v);
                    else           xr[(size_t)node * 128 + (col - 128)] = v;
                }
            }
        }
    }
}

// ============ fused per-node softmax aggregation ============
// One wave per dst node, 4 edges per main iteration (2 per half-wave).
// Score reduction = DPP row_ror rotation-reduce within 16-lane head groups
// (pure VALU; no ds_swizzle/lgkmcnt). Final cross-half combine via shfl_xor(32).
__global__ __launch_bounds__(256) void node_agg_kernel(
    const __half* __restrict__ xl16, const float* __restrict__ xr,
    const float* __restrict__ att,
    const int* __restrict__ off, const int* __restrict__ counts,
    const int* __restrict__ tops, const int* __restrict__ ssrc,
    const float* __restrict__ bias, float* __restrict__ out) {
    const int node = (blockIdx.x * blockDim.x + threadIdx.x) >> 6;
    const int lane = threadIdx.x & 63;
    if (node >= N_NODES) return;
    const int half = lane >> 5;
    const int cl   = lane & 31;

    const uint2* __restrict__ xlh = (const uint2*)xl16;
    const float4 xrv  = ((const float4*)xr)[node * 32 + cl];
    const float4 attv = ((const float4*)att)[cl];

    const int cnt = counts[node];
    const int o   = tops[node >> 8] + off[node];

    float d = 0.0f;
    float4 acc = {0.0f, 0.0f, 0.0f, 0.0f};

#define LOADV(raw, v)                                                        \
    {                                                                        \
        __half2 h01 = *(__half2*)&raw.x;                                     \
        __half2 h23 = *(__half2*)&raw.y;                                     \
        float2 f01 = __half22float2(h01);                                    \
        float2 f23 = __half22float2(h23);                                    \
        v.x = f01.x; v.y = f01.y; v.z = f23.x; v.w = f23.y;                  \
    }
#define SCORE(v, a)                                                          \
    {                                                                        \
        float s0 = v.x + xrv.x; s0 = fmaxf(s0, NEG_SLOPE * s0);              \
        float s1 = v.y + xrv.y; s1 = fmaxf(s1, NEG_SLOPE * s1);              \
        float s2 = v.z + xrv.z; s2 = fmaxf(s2, NEG_SLOPE * s2);              \
        float s3 = v.w + xrv.w; s3 = fmaxf(s3, NEG_SLOPE * s3);              \
        a = fmaf(s0, attv.x, fmaf(s1, attv.y, fmaf(s2, attv.z, s3 * attv.w))); \
    }

    int k = 0;
    for (; k + 4 <= cnt; k += 4) {
        const int sA = ssrc[o + k + half];
        const int sB = ssrc[o + k + 2 + half];
        const uint2 rA = xlh[sA * 32 + cl];
        const uint2 rB = xlh[sB * 32 + cl];
        float4 vA, vB;
        LOADV(rA, vA);
        LOADV(rB, vB);

        float a0, a1;
        SCORE(vA, a0);
        SCORE(vB, a1);
        REDUCE16(a0);
        REDUCE16(a1);
        const float wA = __expf(a0);
        const float wB = __expf(a1);
        d += wA + wB;
        acc.x = fmaf(wA, vA.x, fmaf(wB, vB.x, acc.x));
        acc.y = fmaf(wA, vA.y, fmaf(wB, vB.y, acc.y));
        acc.z = fmaf(wA, vA.z, fmaf(wB, vB.z, acc.z));
        acc.w = fmaf(wA, vA.w, fmaf(wB, vB.w, acc.w));
    }
    for (; k < cnt; k += 2) {
        const int eidx = k + half;
        const bool valid = (eidx < cnt);
        const int src = ssrc[o + (valid ? eidx : 0)];
        const uint2 raw = xlh[src * 32 + cl];
        float4 v;
        LOADV(raw, v);
        float a;
        SCORE(v, a);
        REDUCE16(a);
        const float w = valid ? __expf(a) : 0.0f;
        d += w;
        acc.x = fmaf(w, v.x, acc.x);
        acc.y = fmaf(w, v.y, acc.y);
        acc.z = fmaf(w, v.z, acc.z);
        acc.w = fmaf(w, v.w, acc.w);
    }
#undef SCORE
#undef LOADV
    acc.x += __shfl_xor(acc.x, 32);
    acc.y += __shfl_xor(acc.y, 32);
    acc.z += __shfl_xor(acc.z, 32);
    acc.w += __shfl_xor(acc.w, 32);
    d     += __shfl_xor(d, 32);

    if (lane < 32) {
        const float4 bv = ((const float4*)bias)[cl];
        const float inv = 1.0f / (d + 1e-16f);
        float4 r;
        float t;
        t = __expf(2.0f * fmaf(acc.x, inv, bv.x)); r.x = (t - 1.0f) / (t + 1.0f);
        t = __expf(2.0f * fmaf(acc.y, inv, bv.y)); r.y = (t - 1.0f) / (t + 1.0f);
        t = __expf(2.0f * fmaf(acc.z, inv, bv.z)); r.z = (t - 1.0f) / (t + 1.0f);
        t = __expf(2.0f * fmaf(acc.w, inv, bv.w)); r.w = (t - 1.0f) / (t + 1.0f);
        ((float4*)out)[node * 32 + cl] = r;
    }
}

extern "C" void kernel_launch(void* const* d_in, const int* in_sizes, int n_in,
                              void* d_out, int out_size, void* d_ws, size_t ws_size,
                              hipStream_t stream) {
    const float* x    = (const float*)d_in[0];
    const int*   ei   = (const int*)d_in[1];
    // d_in[2] = edge_weight — unused by the reference
    const float* Wl   = (const float*)d_in[3];
    const float* bl   = (const float*)d_in[4];
    const float* Wr   = (const float*)d_in[5];
    const float* br   = (const float*)d_in[6];
    const float* att  = (const float*)d_in[7];
    const float* bias = (const float*)d_in[8];
    float* out = (float*)d_out;

    // workspace layout
    char* ws = (char*)d_ws;
    __half* xl16  = (__half*)ws;  ws += (size_t)N_NODES * OUT_CH * 2;
    float*  xr    = (float*)ws;   ws += (size_t)N_NODES * OUT_CH * 4;
    __half* wfrag = (__half*)ws;  ws += (size_t)256 * 128 * 2;
    float*  bcat  = (float*)ws;   ws += 256 * 4;
    int*   counts = (int*)ws;     ws += (size_t)N_NODES * 4;
    int*   off    = (int*)ws;     ws += (size_t)N_NODES * 4;
    int*   tops   = (int*)ws;     ws += 256 * 4;
    int*   rank   = (int*)ws;     ws += (size_t)E_EDGES * 4;
    int*   ssrc   = (int*)ws;     ws += (size_t)E_EDGES * 4;

    const int pairBlocks = (E_EDGES / 2 + 255) / 256;     // 1563

    convW_kernel<<<NBLK_SCAN, 256, 0, stream>>>(Wl, bl, Wr, br, wfrag, bcat, counts);
    linear_mfma_kernel<<<(N_NODES + 63) / 64, 256, 0, stream>>>(x, wfrag, bcat, xl16, xr);
    count_kernel<<<pairBlocks, 256, 0, stream>>>(ei, counts, rank);
    scan1_kernel<<<NBLK_SCAN, 256, 0, stream>>>(counts, off, tops);
    scan2_kernel<<<1, 256, 0, stream>>>(tops);
    scatter_kernel<<<pairBlocks, 256, 0, stream>>>(ei, off, tops, rank, ssrc);
    node_agg_kernel<<<(N_NODES + 3) / 4, 256, 0, stream>>>(
        xl16, xr, att, off, counts, tops, ssrc, bias, out);
}

// Round 15
// 124.450 us; speedup vs baseline: 1.3716x; 1.0009x over previous
//
#include <hip/hip_runtime.h>
#include <hip/hip_fp16.h>
#include <math.h>

#define N_NODES 50000
#define E_EDGES 800000
#define IN_CH   128
#define OUT_CH  128   // HEADS*HID
#define HID     64
#define NEG_SLOPE 0.2f
#define NBLK_SCAN ((N_NODES + 255) / 256)   // 196
#define XS_STRIDE 136                       // 128 + 8 fp16 pad (272B rows)

typedef _Float16 half8 __attribute__((ext_vector_type(8)));
typedef _Float16 h2 __attribute__((ext_vector_type(2)));
typedef float f32x2 __attribute__((ext_vector_type(2)));
typedef float f32x4 __attribute__((ext_vector_type(4)));

// DPP rotation-reduce step within each 16-lane row: a += row_ror<N>(a).
// Pure VALU (no ds_swizzle / lgkmcnt).
template<int CTRL>
__device__ __forceinline__ float dpp_add(float a) {
    int t = __builtin_amdgcn_update_dpp(0, __float_as_int(a), CTRL, 0xF, 0xF, true);
    return a + __int_as_float(t);
}
// row_ror:N ctrl encoding = 0x120 | N
#define REDUCE16(a)                                                          \
    a = dpp_add<0x128>(a); a = dpp_add<0x124>(a);                            \
    a = dpp_add<0x122>(a); a = dpp_add<0x121>(a);

// ============ CSR build ============

// 2 edges per thread; atomicAdd's return value IS the edge's rank within its
// dst segment -> stored for an atomic-free scatter.
__global__ void count_kernel(const int* __restrict__ ei, int* __restrict__ counts,
                             int* __restrict__ rank) {
    int t = blockIdx.x * blockDim.x + threadIdx.x;
    if (t * 2 < E_EDGES) {
        int2 d = *(const int2*)(ei + E_EDGES + t * 2);
        int2 r;
        r.x = atomicAdd(&counts[d.x], 1);
        r.y = atomicAdd(&counts[d.y], 1);
        *(int2*)(rank + t * 2) = r;
    }
}

__global__ __launch_bounds__(256) void scan1_kernel(const int* __restrict__ counts,
                                                    int* __restrict__ off,
                                                    int* __restrict__ tops) {
    __shared__ int s[256];
    int i = blockIdx.x * 256 + threadIdx.x;
    int v = (i < N_NODES) ? counts[i] : 0;
    s[threadIdx.x] = v;
    __syncthreads();
    for (int dlt = 1; dlt < 256; dlt <<= 1) {
        int t = (threadIdx.x >= dlt) ? s[threadIdx.x - dlt] : 0;
        __syncthreads();
        s[threadIdx.x] += t;
        __syncthreads();
    }
    if (i < N_NODES) off[i] = s[threadIdx.x] - v;   // exclusive within block
    if (threadIdx.x == 255) tops[blockIdx.x] = s[255];
}

__global__ __launch_bounds__(256) void scan2_kernel(int* __restrict__ tops) {
    __shared__ int s[256];
    int v = (threadIdx.x < NBLK_SCAN) ? tops[threadIdx.x] : 0;
    s[threadIdx.x] = v;
    __syncthreads();
    for (int dlt = 1; dlt < 256; dlt <<= 1) {
        int t = (threadIdx.x >= dlt) ? s[threadIdx.x - dlt] : 0;
        __syncthreads();
        s[threadIdx.x] += t;
        __syncthreads();
    }
    if (threadIdx.x < NBLK_SCAN) tops[threadIdx.x] = s[threadIdx.x] - v;  // exclusive
}

// atomic-free scatter: pos = segment start + precomputed rank
__global__ void scatter_kernel(const int* __restrict__ ei, const int* __restrict__ off,
                               const int* __restrict__ tops, const int* __restrict__ rank,
                               int* __restrict__ ssrc) {
    int t = blockIdx.x * blockDim.x + threadIdx.x;
    if (t * 2 >= E_EDGES) return;
    int2 d = *(const int2*)(ei + E_EDGES + t * 2);
    int2 s = *(const int2*)(ei + t * 2);
    int2 r = *(const int2*)(rank + t * 2);
    ssrc[tops[d.x >> 8] + off[d.x] + r.x] = s.x;
    ssrc[tops[d.y >> 8] + off[d.y] + r.y] = s.y;
}

// ============ prep: W in MFMA-fragment order + bcat + zero counts ============
__global__ __launch_bounds__(256) void convW_kernel(
    const float* __restrict__ Wl, const float* __restrict__ bl,
    const float* __restrict__ Wr, const float* __restrict__ br,
    __half* __restrict__ wfrag, float* __restrict__ bcat,
    int* __restrict__ counts) {
    const int gid = blockIdx.x * 256 + threadIdx.x;
    if (gid < N_NODES) counts[gid] = 0;
    if (gid >= 4096) return;
    const int n = gid & 255;          // output col in [0,256)
    const int c = gid >> 8;           // k-chunk in [0,16)
    const int t = n >> 4, q16 = n & 15, s = c >> 2, kg = c & 3;
    const int k0 = c * 8;
    const float* __restrict__ Wsrc = (n < 128) ? Wl : Wr;
    const int col = n & 127;
    half8 h;
    #pragma unroll
    for (int j = 0; j < 8; ++j) h[j] = (_Float16)Wsrc[(k0 + j) * 128 + col];
    ((half8*)wfrag)[((t * 4 + s) * 4 + kg) * 16 + q16] = h;
    if (c == 0) bcat[n] = (n < 128) ? bl[col] : br[col];
}

// ============ dense via MFMA: [xl16|xr] = x @ [Wl|Wr] + [bl|br] ============
__global__ __launch_bounds__(256) void linear_mfma_kernel(
    const float* __restrict__ x, const __half* __restrict__ wfrag,
    const float* __restrict__ bcat,
    __half* __restrict__ xl16, float* __restrict__ xr) {
    __shared__ __align__(16) __half xs[64 * XS_STRIDE];
    const int tid  = threadIdx.x;
    const int lane = tid & 63;
    const int wv   = tid >> 6;
    const int nodeBase = blockIdx.x * 64;

    {
        const float4* __restrict__ x4 = (const float4*)(x + (size_t)nodeBase * IN_CH);
        #pragma unroll
        for (int i = 0; i < 8; ++i) {
            const int idx = tid + i * 256;      // float4 index in [0,2048)
            const int row = idx >> 5;
            const int c   = (idx & 31) * 4;
            float4 v = {0.0f, 0.0f, 0.0f, 0.0f};
            if (nodeBase + row < N_NODES) v = x4[idx];
            __half2 h01 = __floats2half2_rn(v.x, v.y);
            __half2 h23 = __floats2half2_rn(v.z, v.w);
            uint2 pk;
            pk.x = *(unsigned int*)&h01;
            pk.y = *(unsigned int*)&h23;
            *(uint2*)&xs[row * XS_STRIDE + c] = pk;
        }
    }
    __syncthreads();

    const int q16 = lane & 15;
    const int kg  = lane >> 4;

    const half8* __restrict__ wf8 = (const half8*)wfrag;
    half8 b[4][4];
    #pragma unroll
    for (int t = 0; t < 4; ++t)
        #pragma unroll
        for (int s = 0; s < 4; ++s)
            b[t][s] = wf8[(((wv * 4 + t) * 4 + s) * 4 + kg) * 16 + q16];

    #pragma unroll
    for (int m = 0; m < 4; ++m) {
        f32x4 acc[4];
        #pragma unroll
        for (int t = 0; t < 4; ++t) acc[t] = (f32x4){0.0f, 0.0f, 0.0f, 0.0f};
        #pragma unroll
        for (int s = 0; s < 4; ++s) {
            const half8 a = *(const half8*)&xs[(m * 16 + q16) * XS_STRIDE + s * 32 + kg * 8];
            #pragma unroll
            for (int t = 0; t < 4; ++t)
                acc[t] = __builtin_amdgcn_mfma_f32_16x16x32_f16(a, b[t][s], acc[t], 0, 0, 0);
        }
        const int nodeRow0 = nodeBase + m * 16 + kg * 4;
        #pragma unroll
        for (int t = 0; t < 4; ++t) {
            const int col = wv * 64 + t * 16 + q16;
            const float bv = bcat[col];
            #pragma unroll
            for (int r = 0; r < 4; ++r) {
                const int node = nodeRow0 + r;
                if (node < N_NODES) {
                    const float v = acc[t][r] + bv;
                    if (col < 128) xl16[(size_t)node * 128 + col] = __float2half_rn(v);
                    else           xr[(size_t)node * 128 + (col - 128)] = v;
                }
            }
        }
    }
}

// ============ fused per-node softmax aggregation ============
// One wave per dst node, 4 edges per main iteration (2 per half-wave).
// Score path in PACKED FP16 via native _Float16 vectors: v_pk_add/mul/max_f16
// + v_dot2_f32_f16 (xr/att fp16 conversion error is common-mode per node ->
// cancels in softmax). Accumulation stays fp32. Reduction = DPP row_ror.
__global__ __launch_bounds__(256) void node_agg_kernel(
    const __half* __restrict__ xl16, const float* __restrict__ xr,
    const float* __restrict__ att,
    const int* __restrict__ off, const int* __restrict__ counts,
    const int* __restrict__ tops, const int* __restrict__ ssrc,
    const float* __restrict__ bias, float* __restrict__ out) {
    const int node = (blockIdx.x * blockDim.x + threadIdx.x) >> 6;
    const int lane = threadIdx.x & 63;
    if (node >= N_NODES) return;
    const int half = lane >> 5;
    const int cl   = lane & 31;

    const uint2* __restrict__ xlh = (const uint2*)xl16;
    const float4 xrv  = ((const float4*)xr)[node * 32 + cl];
    const float4 attv = ((const float4*)att)[cl];
    const h2 xr01  = {(_Float16)xrv.x, (_Float16)xrv.y};
    const h2 xr23  = {(_Float16)xrv.z, (_Float16)xrv.w};
    const h2 att01 = {(_Float16)attv.x, (_Float16)attv.y};
    const h2 att23 = {(_Float16)attv.z, (_Float16)attv.w};
    const h2 ns2   = {(_Float16)NEG_SLOPE, (_Float16)NEG_SLOPE};

    const int cnt = counts[node];
    const int o   = tops[node >> 8] + off[node];

    float d = 0.0f;
    float4 acc = {0.0f, 0.0f, 0.0f, 0.0f};

// packed-fp16 score: a = dot(leakyrelu(v + xr), att) for this lane's 4 channels
// (macro params chosen to NOT collide with member tokens .x/.y/.z/.w)
#define SCOREH(raw, aout)                                                    \
    {                                                                        \
        h2 v01 = *(h2*)&raw.x;                                               \
        h2 v23 = *(h2*)&raw.y;                                               \
        h2 s01 = v01 + xr01;                                                 \
        h2 s23 = v23 + xr23;                                                 \
        h2 l01 = __builtin_elementwise_max(s01, s01 * ns2);                  \
        h2 l23 = __builtin_elementwise_max(s23, s23 * ns2);                  \
        aout = __builtin_amdgcn_fdot2(l01, att01,                            \
               __builtin_amdgcn_fdot2(l23, att23, 0.0f, false), false);      \
    }
#define ACCUM(raw, wgt)                                                      \
    {                                                                        \
        f32x2 f01 = __builtin_convertvector(*(h2*)&raw.x, f32x2);            \
        f32x2 f23 = __builtin_convertvector(*(h2*)&raw.y, f32x2);            \
        d += wgt;                                                            \
        acc.x = fmaf(wgt, f01.x, acc.x);                                     \
        acc.y = fmaf(wgt, f01.y, acc.y);                                     \
        acc.z = fmaf(wgt, f23.x, acc.z);                                     \
        acc.w = fmaf(wgt, f23.y, acc.w);                                     \
    }

    int k = 0;
    for (; k + 4 <= cnt; k += 4) {
        const int sA = ssrc[o + k + half];
        const int sB = ssrc[o + k + 2 + half];
        const uint2 rA = xlh[sA * 32 + cl];
        const uint2 rB = xlh[sB * 32 + cl];
        float a0, a1;
        SCOREH(rA, a0);
        SCOREH(rB, a1);
        REDUCE16(a0);
        REDUCE16(a1);
        const float eA = __expf(a0);
        const float eB = __expf(a1);
        ACCUM(rA, eA);
        ACCUM(rB, eB);
    }
    for (; k < cnt; k += 2) {
        const int eidx = k + half;
        const bool valid = (eidx < cnt);
        const int src = ssrc[o + (valid ? eidx : 0)];
        const uint2 raw = xlh[src * 32 + cl];
        float a;
        SCOREH(raw, a);
        REDUCE16(a);
        const float ev = valid ? __expf(a) : 0.0f;
        ACCUM(raw, ev);
    }
#undef SCOREH
#undef ACCUM
    acc.x += __shfl_xor(acc.x, 32);
    acc.y += __shfl_xor(acc.y, 32);
    acc.z += __shfl_xor(acc.z, 32);
    acc.w += __shfl_xor(acc.w, 32);
    d     += __shfl_xor(d, 32);

    if (lane < 32) {
        const float4 bv = ((const float4*)bias)[cl];
        const float inv = 1.0f / (d + 1e-16f);
        float4 r;
        float t;
        t = __expf(2.0f * fmaf(acc.x, inv, bv.x)); r.x = (t - 1.0f) / (t + 1.0f);
        t = __expf(2.0f * fmaf(acc.y, inv, bv.y)); r.y = (t - 1.0f) / (t + 1.0f);
        t = __expf(2.0f * fmaf(acc.z, inv, bv.z)); r.z = (t - 1.0f) / (t + 1.0f);
        t = __expf(2.0f * fmaf(acc.w, inv, bv.w)); r.w = (t - 1.0f) / (t + 1.0f);
        ((float4*)out)[node * 32 + cl] = r;
    }
}

extern "C" void kernel_launch(void* const* d_in, const int* in_sizes, int n_in,
                              void* d_out, int out_size, void* d_ws, size_t ws_size,
                              hipStream_t stream) {
    const float* x    = (const float*)d_in[0];
    const int*   ei   = (const int*)d_in[1];
    // d_in[2] = edge_weight — unused by the reference
    const float* Wl   = (const float*)d_in[3];
    const float* bl   = (const float*)d_in[4];
    const float* Wr   = (const float*)d_in[5];
    const float* br   = (const float*)d_in[6];
    const float* att  = (const float*)d_in[7];
    const float* bias = (const float*)d_in[8];
    float* out = (float*)d_out;

    // workspace layout
    char* ws = (char*)d_ws;
    __half* xl16  = (__half*)ws;  ws += (size_t)N_NODES * OUT_CH * 2;
    float*  xr    = (float*)ws;   ws += (size_t)N_NODES * OUT_CH * 4;
    __half* wfrag = (__half*)ws;  ws += (size_t)256 * 128 * 2;
    float*  bcat  = (float*)ws;   ws += 256 * 4;
    int*   counts = (int*)ws;     ws += (size_t)N_NODES * 4;
    int*   off    = (int*)ws;     ws += (size_t)N_NODES * 4;
    int*   tops   = (int*)ws;     ws += 256 * 4;
    int*   rank   = (int*)ws;     ws += (size_t)E_EDGES * 4;
    int*   ssrc   = (int*)ws;     ws += (size_t)E_EDGES * 4;

    const int pairBlocks = (E_EDGES / 2 + 255) / 256;     // 1563

    convW_kernel<<<NBLK_SCAN, 256, 0, stream>>>(Wl, bl, Wr, br, wfrag, bcat, counts);
    linear_mfma_kernel<<<(N_NODES + 63) / 64, 256, 0, stream>>>(x, wfrag, bcat, xl16, xr);
    count_kernel<<<pairBlocks, 256, 0, stream>>>(ei, counts, rank);
    scan1_kernel<<<NBLK_SCAN, 256, 0, stream>>>(counts, off, tops);
    scan2_kernel<<<1, 256, 0, stream>>>(tops);
    scatter_kernel<<<pairBlocks, 256, 0, stream>>>(ei, off, tops, rank, ssrc);
    node_agg_kernel<<<(N_NODES + 3) / 4, 256, 0, stream>>>(
        xl16, xr, att, off, counts, tops, ssrc, bias, out);
}

// Round 16
// 122.993 us; speedup vs baseline: 1.3879x; 1.0119x over previous
//
#include <hip/hip_runtime.h>
#include <hip/hip_fp16.h>
#include <math.h>

#define N_NODES 50000
#define E_EDGES 800000
#define IN_CH   128
#define OUT_CH  128   // HEADS*HID
#define HID     64
#define NEG_SLOPE 0.2f
#define NBLK_SCAN ((N_NODES + 255) / 256)   // 196
#define XS_STRIDE 136                       // 128 + 8 fp16 pad (272B rows)

typedef _Float16 half8 __attribute__((ext_vector_type(8)));
typedef _Float16 h2 __attribute__((ext_vector_type(2)));
typedef float f32x2 __attribute__((ext_vector_type(2)));
typedef float f32x4 __attribute__((ext_vector_type(4)));

// DPP rotation-reduce step within each 16-lane row: a += row_ror<N>(a).
// Pure VALU (no ds_swizzle / lgkmcnt).
template<int CTRL>
__device__ __forceinline__ float dpp_add(float a) {
    int t = __builtin_amdgcn_update_dpp(0, __float_as_int(a), CTRL, 0xF, 0xF, true);
    return a + __int_as_float(t);
}
// row_ror:N ctrl encoding = 0x120 | N
#define REDUCE16(a)                                                          \
    a = dpp_add<0x128>(a); a = dpp_add<0x124>(a);                            \
    a = dpp_add<0x122>(a); a = dpp_add<0x121>(a);

// ============ CSR build ============

// 2 edges per thread; atomicAdd's return value IS the edge's rank within its
// dst segment -> stored for an atomic-free scatter.
__global__ void count_kernel(const int* __restrict__ ei, int* __restrict__ counts,
                             int* __restrict__ rank) {
    int t = blockIdx.x * blockDim.x + threadIdx.x;
    if (t * 2 < E_EDGES) {
        int2 d = *(const int2*)(ei + E_EDGES + t * 2);
        int2 r;
        r.x = atomicAdd(&counts[d.x], 1);
        r.y = atomicAdd(&counts[d.y], 1);
        *(int2*)(rank + t * 2) = r;
    }
}

__global__ __launch_bounds__(256) void scan1_kernel(const int* __restrict__ counts,
                                                    int* __restrict__ off,
                                                    int* __restrict__ tops) {
    __shared__ int s[256];
    int i = blockIdx.x * 256 + threadIdx.x;
    int v = (i < N_NODES) ? counts[i] : 0;
    s[threadIdx.x] = v;
    __syncthreads();
    for (int dlt = 1; dlt < 256; dlt <<= 1) {
        int t = (threadIdx.x >= dlt) ? s[threadIdx.x - dlt] : 0;
        __syncthreads();
        s[threadIdx.x] += t;
        __syncthreads();
    }
    if (i < N_NODES) off[i] = s[threadIdx.x] - v;   // exclusive within block
    if (threadIdx.x == 255) tops[blockIdx.x] = s[255];
}

__global__ __launch_bounds__(256) void scan2_kernel(int* __restrict__ tops) {
    __shared__ int s[256];
    int v = (threadIdx.x < NBLK_SCAN) ? tops[threadIdx.x] : 0;
    s[threadIdx.x] = v;
    __syncthreads();
    for (int dlt = 1; dlt < 256; dlt <<= 1) {
        int t = (threadIdx.x >= dlt) ? s[threadIdx.x - dlt] : 0;
        __syncthreads();
        s[threadIdx.x] += t;
        __syncthreads();
    }
    if (threadIdx.x < NBLK_SCAN) tops[threadIdx.x] = s[threadIdx.x] - v;  // exclusive
}

// atomic-free scatter: pos = segment start + precomputed rank
__global__ void scatter_kernel(const int* __restrict__ ei, const int* __restrict__ off,
                               const int* __restrict__ tops, const int* __restrict__ rank,
                               int* __restrict__ ssrc) {
    int t = blockIdx.x * blockDim.x + threadIdx.x;
    if (t * 2 >= E_EDGES) return;
    int2 d = *(const int2*)(ei + E_EDGES + t * 2);
    int2 s = *(const int2*)(ei + t * 2);
    int2 r = *(const int2*)(rank + t * 2);
    ssrc[tops[d.x >> 8] + off[d.x] + r.x] = s.x;
    ssrc[tops[d.y >> 8] + off[d.y] + r.y] = s.y;
}

// ============ prep: W in MFMA-fragment order + bcat + zero counts ============
__global__ __launch_bounds__(256) void convW_kernel(
    const float* __restrict__ Wl, const float* __restrict__ bl,
    const float* __restrict__ Wr, const float* __restrict__ br,
    __half* __restrict__ wfrag, float* __restrict__ bcat,
    int* __restrict__ counts) {
    const int gid = blockIdx.x * 256 + threadIdx.x;
    if (gid < N_NODES) counts[gid] = 0;
    if (gid >= 4096) return;
    const int n = gid & 255;          // output col in [0,256)
    const int c = gid >> 8;           // k-chunk in [0,16)
    const int t = n >> 4, q16 = n & 15, s = c >> 2, kg = c & 3;
    const int k0 = c * 8;
    const float* __restrict__ Wsrc = (n < 128) ? Wl : Wr;
    const int col = n & 127;
    half8 h;
    #pragma unroll
    for (int j = 0; j < 8; ++j) h[j] = (_Float16)Wsrc[(k0 + j) * 128 + col];
    ((half8*)wfrag)[((t * 4 + s) * 4 + kg) * 16 + q16] = h;
    if (c == 0) bcat[n] = (n < 128) ? bl[col] : br[col];
}

// ============ dense via MFMA: [xl16|xr] = x @ [Wl|Wr] + [bl|br] ============
__global__ __launch_bounds__(256) void linear_mfma_kernel(
    const float* __restrict__ x, const __half* __restrict__ wfrag,
    const float* __restrict__ bcat,
    __half* __restrict__ xl16, float* __restrict__ xr) {
    __shared__ __align__(16) __half xs[64 * XS_STRIDE];
    const int tid  = threadIdx.x;
    const int lane = tid & 63;
    const int wv   = tid >> 6;
    const int nodeBase = blockIdx.x * 64;

    {
        const float4* __restrict__ x4 = (const float4*)(x + (size_t)nodeBase * IN_CH);
        #pragma unroll
        for (int i = 0; i < 8; ++i) {
            const int idx = tid + i * 256;      // float4 index in [0,2048)
            const int row = idx >> 5;
            const int c   = (idx & 31) * 4;
            float4 v = {0.0f, 0.0f, 0.0f, 0.0f};
            if (nodeBase + row < N_NODES) v = x4[idx];
            __half2 h01 = __floats2half2_rn(v.x, v.y);
            __half2 h23 = __floats2half2_rn(v.z, v.w);
            uint2 pk;
            pk.x = *(unsigned int*)&h01;
            pk.y = *(unsigned int*)&h23;
            *(uint2*)&xs[row * XS_STRIDE + c] = pk;
        }
    }
    __syncthreads();

    const int q16 = lane & 15;
    const int kg  = lane >> 4;

    const half8* __restrict__ wf8 = (const half8*)wfrag;
    half8 b[4][4];
    #pragma unroll
    for (int t = 0; t < 4; ++t)
        #pragma unroll
        for (int s = 0; s < 4; ++s)
            b[t][s] = wf8[(((wv * 4 + t) * 4 + s) * 4 + kg) * 16 + q16];

    #pragma unroll
    for (int m = 0; m < 4; ++m) {
        f32x4 acc[4];
        #pragma unroll
        for (int t = 0; t < 4; ++t) acc[t] = (f32x4){0.0f, 0.0f, 0.0f, 0.0f};
        #pragma unroll
        for (int s = 0; s < 4; ++s) {
            const half8 a = *(const half8*)&xs[(m * 16 + q16) * XS_STRIDE + s * 32 + kg * 8];
            #pragma unroll
            for (int t = 0; t < 4; ++t)
                acc[t] = __builtin_amdgcn_mfma_f32_16x16x32_f16(a, b[t][s], acc[t], 0, 0, 0);
        }
        const int nodeRow0 = nodeBase + m * 16 + kg * 4;
        #pragma unroll
        for (int t = 0; t < 4; ++t) {
            const int col = wv * 64 + t * 16 + q16;
            const float bv = bcat[col];
            #pragma unroll
            for (int r = 0; r < 4; ++r) {
                const int node = nodeRow0 + r;
                if (node < N_NODES) {
                    const float v = acc[t][r] + bv;
                    if (col < 128) xl16[(size_t)node * 128 + col] = __float2half_rn(v);
                    else           xr[(size_t)node * 128 + (col - 128)] = v;
                }
            }
        }
    }
}

// ============ fused per-node softmax aggregation ============
// PERSISTENT grid-stride waves (load-balances Poisson degrees); 8 edges per
// main iteration (4 independent gathers per half-wave -> 2x memory-level
// parallelism). Packed-fp16 score path; fp32 accumulation; DPP reductions.
__global__ __launch_bounds__(256) void node_agg_kernel(
    const __half* __restrict__ xl16, const float* __restrict__ xr,
    const float* __restrict__ att,
    const int* __restrict__ off, const int* __restrict__ counts,
    const int* __restrict__ tops, const int* __restrict__ ssrc,
    const float* __restrict__ bias, float* __restrict__ out) {
    const int lane = threadIdx.x & 63;
    const int half = lane >> 5;
    const int cl   = lane & 31;
    const int wid    = (blockIdx.x * blockDim.x + threadIdx.x) >> 6;
    const int nwaves = (gridDim.x * blockDim.x) >> 6;

    const uint2* __restrict__ xlh = (const uint2*)xl16;
    const float4 attv = ((const float4*)att)[cl];
    const h2 att01 = {(_Float16)attv.x, (_Float16)attv.y};
    const h2 att23 = {(_Float16)attv.z, (_Float16)attv.w};
    const h2 ns2   = {(_Float16)NEG_SLOPE, (_Float16)NEG_SLOPE};
    const float4 bv = ((const float4*)bias)[cl];

// packed-fp16 score: a = dot(leakyrelu(v + xr), att) for this lane's 4 channels
#define SCOREH(raw, aout)                                                    \
    {                                                                        \
        h2 v01 = *(h2*)&raw.x;                                               \
        h2 v23 = *(h2*)&raw.y;                                               \
        h2 s01 = v01 + xr01;                                                 \
        h2 s23 = v23 + xr23;                                                 \
        h2 l01 = __builtin_elementwise_max(s01, s01 * ns2);                  \
        h2 l23 = __builtin_elementwise_max(s23, s23 * ns2);                  \
        aout = __builtin_amdgcn_fdot2(l01, att01,                            \
               __builtin_amdgcn_fdot2(l23, att23, 0.0f, false), false);      \
    }
#define ACCUM(raw, wgt)                                                      \
    {                                                                        \
        f32x2 f01 = __builtin_convertvector(*(h2*)&raw.x, f32x2);            \
        f32x2 f23 = __builtin_convertvector(*(h2*)&raw.y, f32x2);            \
        d += wgt;                                                            \
        acc.x = fmaf(wgt, f01.x, acc.x);                                     \
        acc.y = fmaf(wgt, f01.y, acc.y);                                     \
        acc.z = fmaf(wgt, f23.x, acc.z);                                     \
        acc.w = fmaf(wgt, f23.y, acc.w);                                     \
    }

    for (int node = wid; node < N_NODES; node += nwaves) {
        const float4 xrv = ((const float4*)xr)[node * 32 + cl];
        const h2 xr01 = {(_Float16)xrv.x, (_Float16)xrv.y};
        const h2 xr23 = {(_Float16)xrv.z, (_Float16)xrv.w};

        const int cnt = counts[node];
        const int o   = tops[node >> 8] + off[node];

        float d = 0.0f;
        float4 acc = {0.0f, 0.0f, 0.0f, 0.0f};

        int k = 0;
        // main: 8 edges per iteration (4 per half-wave, all gathers independent)
        for (; k + 8 <= cnt; k += 8) {
            const int base = o + k + 4 * half;
            const int sA = ssrc[base + 0];
            const int sB = ssrc[base + 1];
            const int sC = ssrc[base + 2];
            const int sD = ssrc[base + 3];
            const uint2 rA = xlh[sA * 32 + cl];
            const uint2 rB = xlh[sB * 32 + cl];
            const uint2 rC = xlh[sC * 32 + cl];
            const uint2 rD = xlh[sD * 32 + cl];
            float a0, a1, a2, a3;
            SCOREH(rA, a0);
            SCOREH(rB, a1);
            SCOREH(rC, a2);
            SCOREH(rD, a3);
            REDUCE16(a0);
            REDUCE16(a1);
            REDUCE16(a2);
            REDUCE16(a3);
            const float eA = __expf(a0);
            const float eB = __expf(a1);
            const float eC = __expf(a2);
            const float eD = __expf(a3);
            ACCUM(rA, eA);
            ACCUM(rB, eB);
            ACCUM(rC, eC);
            ACCUM(rD, eD);
        }
        // mid: 4 edges (2 per half-wave)
        for (; k + 4 <= cnt; k += 4) {
            const int sA = ssrc[o + k + half];
            const int sB = ssrc[o + k + 2 + half];
            const uint2 rA = xlh[sA * 32 + cl];
            const uint2 rB = xlh[sB * 32 + cl];
            float a0, a1;
            SCOREH(rA, a0);
            SCOREH(rB, a1);
            REDUCE16(a0);
            REDUCE16(a1);
            const float eA = __expf(a0);
            const float eB = __expf(a1);
            ACCUM(rA, eA);
            ACCUM(rB, eB);
        }
        // tail: up to 3 edges, pair-style with predication
        for (; k < cnt; k += 2) {
            const int eidx = k + half;
            const bool valid = (eidx < cnt);
            const int src = ssrc[o + (valid ? eidx : 0)];
            const uint2 raw = xlh[src * 32 + cl];
            float a;
            SCOREH(raw, a);
            REDUCE16(a);
            const float ev = valid ? __expf(a) : 0.0f;
            ACCUM(raw, ev);
        }
        // combine the two half-wave partial sums
        acc.x += __shfl_xor(acc.x, 32);
        acc.y += __shfl_xor(acc.y, 32);
        acc.z += __shfl_xor(acc.z, 32);
        acc.w += __shfl_xor(acc.w, 32);
        d     += __shfl_xor(d, 32);

        if (lane < 32) {
            const float inv = 1.0f / (d + 1e-16f);
            float4 r;
            float t;
            t = __expf(2.0f * fmaf(acc.x, inv, bv.x)); r.x = (t - 1.0f) / (t + 1.0f);
            t = __expf(2.0f * fmaf(acc.y, inv, bv.y)); r.y = (t - 1.0f) / (t + 1.0f);
            t = __expf(2.0f * fmaf(acc.z, inv, bv.z)); r.z = (t - 1.0f) / (t + 1.0f);
            t = __expf(2.0f * fmaf(acc.w, inv, bv.w)); r.w = (t - 1.0f) / (t + 1.0f);
            ((float4*)out)[node * 32 + cl] = r;
        }
    }
#undef SCOREH
#undef ACCUM
}

extern "C" void kernel_launch(void* const* d_in, const int* in_sizes, int n_in,
                              void* d_out, int out_size, void* d_ws, size_t ws_size,
                              hipStream_t stream) {
    const float* x    = (const float*)d_in[0];
    const int*   ei   = (const int*)d_in[1];
    // d_in[2] = edge_weight — unused by the reference
    const float* Wl   = (const float*)d_in[3];
    const float* bl   = (const float*)d_in[4];
    const float* Wr   = (const float*)d_in[5];
    const float* br   = (const float*)d_in[6];
    const float* att  = (const float*)d_in[7];
    const float* bias = (const float*)d_in[8];
    float* out = (float*)d_out;

    // workspace layout
    char* ws = (char*)d_ws;
    __half* xl16  = (__half*)ws;  ws += (size_t)N_NODES * OUT_CH * 2;
    float*  xr    = (float*)ws;   ws += (size_t)N_NODES * OUT_CH * 4;
    __half* wfrag = (__half*)ws;  ws += (size_t)256 * 128 * 2;
    float*  bcat  = (float*)ws;   ws += 256 * 4;
    int*   counts = (int*)ws;     ws += (size_t)N_NODES * 4;
    int*   off    = (int*)ws;     ws += (size_t)N_NODES * 4;
    int*   tops   = (int*)ws;     ws += 256 * 4;
    int*   rank   = (int*)ws;     ws += (size_t)E_EDGES * 4;
    int*   ssrc   = (int*)ws;     ws += (size_t)E_EDGES * 4;

    const int pairBlocks = (E_EDGES / 2 + 255) / 256;     // 1563

    convW_kernel<<<NBLK_SCAN, 256, 0, stream>>>(Wl, bl, Wr, br, wfrag, bcat, counts);
    linear_mfma_kernel<<<(N_NODES + 63) / 64, 256, 0, stream>>>(x, wfrag, bcat, xl16, xr);
    count_kernel<<<pairBlocks, 256, 0, stream>>>(ei, counts, rank);
    scan1_kernel<<<NBLK_SCAN, 256, 0, stream>>>(counts, off, tops);
    scan2_kernel<<<1, 256, 0, stream>>>(tops);
    scatter_kernel<<<pairBlocks, 256, 0, stream>>>(ei, off, tops, rank, ssrc);
    node_agg_kernel<<<2048, 256, 0, stream>>>(
        xl16, xr, att, off, counts, tops, ssrc, bias, out);
}